// Round 2
// baseline (336.475 us; speedup 1.0000x reference)
//
#include <hip/hip_runtime.h>

// Sparse conv block, output-major formulation:
//   invert rulebook -> dense bins[k][o]={cnt,in0,in1,in2} (+overflow list)
//   -> gather-only MFMA conv (each out row written ONCE, no global atomics)
//   -> BatchNorm (batch stats) -> ReLU.           MI355X / gfx950.

#define N_VOX   100000
#define NPAD    100096                  // multiple of 64, covers padded rows
#define C_INCH  64
#define C_OUTCH 64
#define K3      27
#define M_PAIRS 40000
#define NPAIRS  (K3 * M_PAIRS)          // 1,080,000
#define BN_EPS  1e-5f

// ---- workspace layout (bytes) ----------------------------------------------
#define OFF_WT     0u                       // bf16 Wt[k][c][i]: 221,184
#define OFF_STATS  221184u                  // f32[128]
#define OFF_OVCNT  221696u                  // int
#define OFF_BINS   221760u                  // int4[k][o], 16-aligned
#define SZ_BINS    (27u * NPAD * 16u)       // 43,241,472
#define OFF_OV     (OFF_BINS + SZ_BINS)     // 43,463,232 ; int2[NPAIRS]
#define SZ_OV      ((unsigned)NPAIRS * 8u)  // 8,640,000
#define OFF_XB     (OFF_OV + SZ_OV)         // 52,103,232 ; bf16 x copy
#define WS_NEED    ((size_t)OFF_XB + (size_t)N_VOX * 128u)   // 64,903,232

typedef __attribute__((ext_vector_type(8))) short bf16x8;
typedef __attribute__((ext_vector_type(4))) float f32x4;

__device__ __forceinline__ short f2bf(float f) {
  unsigned u = __builtin_bit_cast(unsigned, f);
  u += 0x7FFFu + ((u >> 16) & 1u);
  return (short)(u >> 16);
}

// ---- W[k][i][c] (f32) -> Wt[k][c][i] (bf16) ---------------------------------
__global__ __launch_bounds__(256) void wconv_kernel(const float* __restrict__ W,
                                                    short* __restrict__ wt) {
  int id = blockIdx.x * 256 + threadIdx.x;
  if (id >= K3 * 4096) return;
  int k   = id >> 12;
  int rem = id & 4095;
  int c   = rem >> 6;
  int i   = rem & 63;
  wt[id] = f2bf(W[(k << 12) + (i << 6) + c]);
}

// ---- x (f32) -> xb (bf16), row-major [N][64] --------------------------------
__global__ __launch_bounds__(256) void xconv_kernel(const float* __restrict__ x,
                                                    short* __restrict__ xb) {
  int id = blockIdx.x * 256 + threadIdx.x;        // 8 elems per thread
  if (id >= N_VOX * 8) return;
  float4 lo = ((const float4*)x)[id * 2];
  float4 hi = ((const float4*)x)[id * 2 + 1];
  bf16x8 v;
  v[0] = f2bf(lo.x); v[1] = f2bf(lo.y); v[2] = f2bf(lo.z); v[3] = f2bf(lo.w);
  v[4] = f2bf(hi.x); v[5] = f2bf(hi.y); v[6] = f2bf(hi.z); v[7] = f2bf(hi.w);
  ((bf16x8*)xb)[id] = v;
}

// ---- invert rulebook: bins[k][o] = {cnt, in0, in1, in2}, overflow list ------
__global__ __launch_bounds__(256) void build_kernel(const int* __restrict__ in_idx,
                                                    const int* __restrict__ out_idx,
                                                    int* __restrict__ bins,
                                                    int2* __restrict__ ov,
                                                    int* __restrict__ ovcnt) {
  int id = blockIdx.x * 256 + threadIdx.x;
  if (id >= NPAIRS) return;
  int k  = id / M_PAIRS;
  int in = in_idx[id];
  int o  = out_idx[id];
  int idx = k * NPAD + o;
  int slot = atomicAdd(&bins[idx * 4], 1);
  if (slot < 3) {
    bins[idx * 4 + 1 + slot] = in;
  } else {
    int p = atomicAdd(ovcnt, 1);
    ov[p] = make_int2((k << 17) | in, o);
  }
}

// ---- gather-only conv: wave owns 16 out rows, loops k, plain stores ---------
// A frag lane l: row = l&15 (out-row slot), k-slots (l>>4)*8+j (+32).
// B frag lane l: col = chan l&15, same k-slot convention.
// C/D: col = lane&15, row = (lane>>4)*4 + reg  [m89-verified, round-1 proven].
#define DO_LAYER(INVAL, LV)                                                        \
  {                                                                                \
    bf16x8 a0 = {0,0,0,0,0,0,0,0}, a1 = {0,0,0,0,0,0,0,0};                         \
    if (cld > (LV)) {                                                              \
      const short* xr = xb + (size_t)(INVAL) * 64;                                 \
      a0 = *(const bf16x8*)(xr + g8);                                              \
      a1 = *(const bf16x8*)(xr + 32 + g8);                                         \
    }                                                                              \
    _Pragma("unroll")                                                              \
    for (int n = 0; n < 4; ++n) {                                                  \
      acc[n] = __builtin_amdgcn_mfma_f32_16x16x32_bf16(a0, b0[n], acc[n], 0, 0, 0);\
      acc[n] = __builtin_amdgcn_mfma_f32_16x16x32_bf16(a1, b1[n], acc[n], 0, 0, 0);\
    }                                                                              \
  }

__global__ __launch_bounds__(256) void conv_out_kernel(const short* __restrict__ xb,
                                                       const short* __restrict__ wt,
                                                       const int* __restrict__ bins,
                                                       float* __restrict__ out) {
  int t    = threadIdx.x;
  int wave = t >> 6, lane = t & 63;
  int g    = lane >> 4, c0 = lane & 15;
  int g8   = g * 8;
  int o_base = blockIdx.x * 64 + wave * 16;
  int o      = o_base + c0;                    // this lane's bin row

  f32x4 acc[4];
  #pragma unroll
  for (int n = 0; n < 4; ++n) { acc[n][0]=0.f; acc[n][1]=0.f; acc[n][2]=0.f; acc[n][3]=0.f; }

  for (int k = 0; k < K3; ++k) {
    int4 b4 = *(const int4*)(bins + (size_t)(k * NPAD + o) * 4);
    int cld = b4.x;
    if (!__any(cld > 0)) continue;
    const short* wtk = wt + k * 4096;
    bf16x8 b0[4], b1[4];
    #pragma unroll
    for (int n = 0; n < 4; ++n) {
      const short* wp = wtk + (n * 16 + c0) * 64 + g8;
      b0[n] = *(const bf16x8*)(wp);
      b1[n] = *(const bf16x8*)(wp + 32);
    }
    DO_LAYER(b4.y, 0);
    if (__any(cld > 1)) {
      DO_LAYER(b4.z, 1);
      if (__any(cld > 2)) DO_LAYER(b4.w, 2);
    }
  }

  int orow = o_base + (g << 2);
  #pragma unroll
  for (int j = 0; j < 4; ++j) {
    if (orow + j < N_VOX) {
      float* op = out + (size_t)(orow + j) * 64 + c0;
      #pragma unroll
      for (int n = 0; n < 4; ++n) op[n * 16] = acc[n][j];
    }
  }
}

// ---- overflow pairs (cnt>=4): one wave per pair, fp32 dot, atomic add -------
__global__ __launch_bounds__(256) void ov_kernel(const float* __restrict__ x,
                                                 const float* __restrict__ W,
                                                 const int2* __restrict__ ov,
                                                 const int* __restrict__ ovcnt,
                                                 float* __restrict__ out) {
  int wid  = (blockIdx.x * 256 + threadIdx.x) >> 6;
  int lane = threadIdx.x & 63;
  int n    = ovcnt[0];
  int nw   = gridDim.x * 4;
  for (int i = wid; i < n; i += nw) {
    int2 e = ov[i];
    int in = e.x & 0x1FFFF;
    int k  = e.x >> 17;
    int o  = e.y;
    const float* xr = x + (size_t)in * 64;
    const float* wp = W + (size_t)k * 4096 + lane;
    float d = 0.f;
    #pragma unroll 8
    for (int ii = 0; ii < 64; ++ii) d += xr[ii] * wp[ii * 64];
    unsafeAtomicAdd(&out[(size_t)o * 64 + lane], d);
  }
}

// ---- legacy (round-1) scatter conv: fallback if ws too small ----------------
__global__ __launch_bounds__(256) void conv_kernel(const float* __restrict__ x,
                                                   const short* __restrict__ wt,
                                                   const int* __restrict__ in_idx,
                                                   const int* __restrict__ out_idx,
                                                   float* __restrict__ out) {
  __shared__ int s_in[64];
  __shared__ int s_out[64];
  int bx   = blockIdx.x;
  int k    = bx / (M_PAIRS / 64);
  int base = (bx % (M_PAIRS / 64)) * 64;
  int t    = threadIdx.x;
  if (t < 64)            s_in[t]       = in_idx[k * M_PAIRS + base + t];
  else if (t < 128)      s_out[t - 64] = out_idx[k * M_PAIRS + base + (t - 64)];
  __syncthreads();
  int wave = t >> 6, lane = t & 63;
  int g = lane >> 4, c0 = lane & 15;
  int prow = (wave << 4) + c0;
  const float* xrow = x + (size_t)s_in[prow] * C_INCH + g * 8;
  float4 a0lo = *(const float4*)(xrow);
  float4 a0hi = *(const float4*)(xrow + 4);
  float4 a1lo = *(const float4*)(xrow + 32);
  float4 a1hi = *(const float4*)(xrow + 36);
  bf16x8 a0, a1;
  a0[0]=f2bf(a0lo.x); a0[1]=f2bf(a0lo.y); a0[2]=f2bf(a0lo.z); a0[3]=f2bf(a0lo.w);
  a0[4]=f2bf(a0hi.x); a0[5]=f2bf(a0hi.y); a0[6]=f2bf(a0hi.z); a0[7]=f2bf(a0hi.w);
  a1[0]=f2bf(a1lo.x); a1[1]=f2bf(a1lo.y); a1[2]=f2bf(a1lo.z); a1[3]=f2bf(a1lo.w);
  a1[4]=f2bf(a1hi.x); a1[5]=f2bf(a1hi.y); a1[6]=f2bf(a1hi.z); a1[7]=f2bf(a1hi.w);
  const short* wtk = wt + k * 4096;
  f32x4 acc[4];
  #pragma unroll
  for (int n = 0; n < 4; ++n) { acc[n][0]=0.f; acc[n][1]=0.f; acc[n][2]=0.f; acc[n][3]=0.f; }
  #pragma unroll
  for (int n = 0; n < 4; ++n) {
    int c = n * 16 + c0;
    bf16x8 b0 = *(const bf16x8*)(wtk + c * 64 + g * 8);
    bf16x8 b1 = *(const bf16x8*)(wtk + c * 64 + 32 + g * 8);
    acc[n] = __builtin_amdgcn_mfma_f32_16x16x32_bf16(a0, b0, acc[n], 0, 0, 0);
    acc[n] = __builtin_amdgcn_mfma_f32_16x16x32_bf16(a1, b1, acc[n], 0, 0, 0);
  }
  int rbase = (wave << 4) + ((lane >> 4) << 2);
  #pragma unroll
  for (int j = 0; j < 4; ++j) {
    size_t o = (size_t)s_out[rbase + j] * C_OUTCH;
    #pragma unroll
    for (int n = 0; n < 4; ++n) unsafeAtomicAdd(&out[o + n * 16 + c0], acc[n][j]);
  }
}

// ---- per-channel sum / sum-of-squares --------------------------------------
__global__ __launch_bounds__(256) void stats_kernel(const float* __restrict__ out,
                                                    float* __restrict__ stats) {
  __shared__ float s1[256], s2[256];
  int t = threadIdx.x;
  int c = t & 63;
  int rsub = t >> 6;
  float sum1 = 0.f, sum2 = 0.f;
  for (int r = blockIdx.x * 4 + rsub; r < N_VOX; r += gridDim.x * 4) {
    float v = out[r * 64 + c];
    sum1 += v;
    sum2 += v * v;
  }
  s1[t] = sum1; s2[t] = sum2;
  __syncthreads();
  if (t < 64) {
    sum1 = s1[t] + s1[t + 64] + s1[t + 128] + s1[t + 192];
    sum2 = s2[t] + s2[t + 64] + s2[t + 128] + s2[t + 192];
    unsafeAtomicAdd(&stats[c], sum1);
    unsafeAtomicAdd(&stats[64 + c], sum2);
  }
}

// ---- finalize BN + ReLU in place -------------------------------------------
__global__ __launch_bounds__(256) void norm_kernel(float* __restrict__ out,
                                                   const float* __restrict__ stats,
                                                   const float* __restrict__ gamma,
                                                   const float* __restrict__ beta) {
  int i4 = blockIdx.x * 256 + threadIdx.x;
  if (i4 >= N_VOX * (C_OUTCH / 4)) return;
  const float invN = 1.0f / (float)N_VOX;
  float4 v = ((const float4*)out)[i4];
  int c0 = (i4 << 2) & 63;
  float r[4] = {v.x, v.y, v.z, v.w};
  #pragma unroll
  for (int j = 0; j < 4; ++j) {
    int c = c0 + j;
    float mean = stats[c] * invN;
    float ex2  = stats[64 + c] * invN;
    float var  = ex2 - mean * mean;
    float scale = gamma[c] * rsqrtf(var + BN_EPS);
    float shift = beta[c] - mean * scale;
    r[j] = fmaxf(r[j] * scale + shift, 0.0f);
  }
  v.x = r[0]; v.y = r[1]; v.z = r[2]; v.w = r[3];
  ((float4*)out)[i4] = v;
}

extern "C" void kernel_launch(void* const* d_in, const int* in_sizes, int n_in,
                              void* d_out, int out_size, void* d_ws, size_t ws_size,
                              hipStream_t stream) {
  const float* x      = (const float*)d_in[0];
  const float* W      = (const float*)d_in[1];
  const float* gamma  = (const float*)d_in[2];
  const float* beta   = (const float*)d_in[3];
  const int*   in_idx = (const int*)d_in[4];
  const int*   out_idx= (const int*)d_in[5];
  float* out = (float*)d_out;

  char* ws = (char*)d_ws;
  short* wt    = (short*)(ws + OFF_WT);
  float* stats = (float*)(ws + OFF_STATS);

  wconv_kernel<<<(K3 * 4096 + 255) / 256, 256, 0, stream>>>(W, wt);
  // zero stats (+ ovcnt pad region)
  hipMemsetAsync(ws + OFF_STATS, 0, OFF_BINS - OFF_STATS, stream);

  if (ws_size >= WS_NEED) {
    int*   ovcnt = (int*)(ws + OFF_OVCNT);
    int*   bins  = (int*)(ws + OFF_BINS);
    int2*  ov    = (int2*)(ws + OFF_OV);
    short* xb    = (short*)(ws + OFF_XB);

    hipMemsetAsync(ws + OFF_BINS, 0, SZ_BINS, stream);
    xconv_kernel<<<(N_VOX * 8 + 255) / 256, 256, 0, stream>>>(x, xb);
    build_kernel<<<(NPAIRS + 255) / 256, 256, 0, stream>>>(in_idx, out_idx, bins, ov, ovcnt);
    conv_out_kernel<<<(N_VOX + 63) / 64, 256, 0, stream>>>(xb, wt, bins, out);
    ov_kernel<<<256, 256, 0, stream>>>(x, W, ov, ovcnt, out);
  } else {
    // fallback: round-1 scatter path
    hipMemsetAsync(d_out, 0, (size_t)N_VOX * C_OUTCH * sizeof(float), stream);
    conv_kernel<<<K3 * (M_PAIRS / 64), 256, 0, stream>>>(x, wt, in_idx, out_idx, out);
  }

  stats_kernel<<<256, 256, 0, stream>>>(out, stats);
  norm_kernel<<<(N_VOX * (C_OUTCH / 4) + 255) / 256, 256, 0, stream>>>(out, stats, gamma, beta);
}